// Round 3
// baseline (75.962 us; speedup 1.0000x reference)
//
#include <hip/hip_runtime.h>
#include <math.h>

// MeshfreeKANNet: out[m] = sum_n phi(m,n) * w[n]
//   phi = windowed+normalized softplus(KAN(diff/radius)), cubic window r=0.06
//   orphan rows (phi_sum < 1e-14) fall back to exp-weighted 8-NN.
// R3 structure: 8 rows per block (256 blocks = 1 block/CU, single round).
//   - nodes (float2) + w staged in LDS once per block (amortized over 8 rows)
//   - each of 4 waves owns 2 rows, fully independent (no __syncthreads after
//     staging): sweep 32 LDS candidates/lane -> ballot-compact actives ->
//     dense KAN on ~23 lanes -> wave shuffle-reduce -> lane0 writes.
//   - orphan kNN fallback is wave-local, recomputing d^2 from LDS (rare).

#define RADIUS 0.06f
#define INV_RADIUS (1.0f / 0.06f)
#define R2C (0.06f * 0.06f)
#define INV_H (4.0f / 3.0f)   // 1/h, h = 0.75
#define MAXN 2048
#define ROWS 8                // rows per block
#define CAP 256               // per-wave compaction capacity (expected ~23)

__device__ __forceinline__ float hatf(float x, float g) {
    return fmaxf(1.0f - fabsf(x - g) * INV_H, 0.0f);
}

// softplus(KAN(dx/r, dy/r)) * cubic_window(sqrt(d2)/r)
__device__ __forceinline__ float kan_phi(float dx, float dy, float d2,
                                         const float* __restrict__ s_w1a,
                                         const float* __restrict__ s_w1b,
                                         const float* __restrict__ s_w2) {
    const float u = dx * INV_RADIUS;
    const float v = dy * INV_RADIUS;
    float b0[5], b1[5];
    #pragma unroll
    for (int i = 0; i < 5; ++i) {
        const float g = -1.5f + 0.75f * (float)i;
        b0[i] = hatf(u, g);
        b1[i] = hatf(v, g);
    }
    float o = 0.0f;
    #pragma unroll
    for (int j = 0; j < 8; ++j) {
        float hj = 0.0f;
        #pragma unroll
        for (int i = 0; i < 5; ++i)
            hj += b0[i] * s_w1a[j * 5 + i] + b1[i] * s_w1b[j * 5 + i];
        #pragma unroll
        for (int g = 0; g < 5; ++g) {
            const float gv = -1.5f + 0.75f * (float)g;
            o += hatf(hj, gv) * s_w2[j * 5 + g];
        }
    }
    // stable softplus (matches jax.nn.softplus in fp32)
    const float sp = fmaxf(o, 0.0f) + log1pf(expf(-fabsf(o)));
    // cubic window on q = d/r
    const float q = sqrtf(d2) * INV_RADIUS;
    float win;
    if (q <= 0.5f) win = 2.0f / 3.0f - 4.0f * q * q + 4.0f * q * q * q;
    else           win = 4.0f / 3.0f - 4.0f * q + 4.0f * q * q
                         - (4.0f / 3.0f) * q * q * q;
    return sp * win;
}

__global__ __launch_bounds__(256) void meshfree_kan_kernel(
    const float* __restrict__ x, const float* __restrict__ nodes,
    const float* __restrict__ w,
    const float* __restrict__ w1a, const float* __restrict__ w1b,
    const float* __restrict__ w2,
    float* __restrict__ out, int M, int N)
{
    const int t = threadIdx.x;
    const int lane = t & 63, wave = t >> 6;
    const float2* __restrict__ nodes2 = (const float2*)nodes;

    __shared__ float2 s_nodes[MAXN];
    __shared__ float  s_w[MAXN];
    __shared__ float  s_w1a[40], s_w1b[40], s_w2[40];
    __shared__ int    s_idx[4][CAP];

    const int NPAD = (N + 63) & ~63;     // N <= MAXN (harness: 2048)
    const int KITER = NPAD >> 6;         // sweep iterations per lane (32)

    // ---- stage nodes, w, and KAN weights into LDS (once per block) ----
    for (int i = t; i < NPAD; i += 256) {
        if (i < N) { s_nodes[i] = nodes2[i]; s_w[i] = w[i]; }
        else       { s_nodes[i] = make_float2(1e15f, 1e15f); s_w[i] = 0.0f; }
    }
    if (t < 40)       s_w1a[t]      = w1a[t];
    else if (t < 80)  s_w1b[t - 40] = w1b[t - 40];
    else if (t < 120) s_w2[t - 80]  = w2[t - 80];
    __syncthreads();
    // waves are fully independent from here on

    #pragma unroll
    for (int r = 0; r < 2; ++r) {
        const int m = blockIdx.x * ROWS + wave * 2 + r;
        if (m >= M) continue;
        const float x0 = x[2 * m], x1 = x[2 * m + 1];

        // ---- Phase A: d^2 sweep + atomic-free wave compaction ----
        int cnt = 0;           // wave-uniform (all lanes track it redundantly)
        float s1 = 0.0f, s2 = 0.0f;
        for (int k = 0; k < KITER; ++k) {
            const int n = lane + (k << 6);
            const float2 p = s_nodes[n];
            const float dx = x0 - p.x;
            const float dy = x1 - p.y;
            const float d2 = fmaf(dx, dx, dy * dy);
            const bool active = (d2 <= R2C);
            const unsigned long long mask = __ballot(active);
            if (active) {
                const int pos = cnt +
                    __popcll(mask & ((1ull << lane) - 1ull));
                if (pos < CAP) {
                    s_idx[wave][pos] = n;
                } else {
                    // overflow (never with this data): evaluate inline
                    const float pw = kan_phi(dx, dy, d2, s_w1a, s_w1b, s_w2);
                    s1 += pw;
                    s2 += pw * s_w[n];
                }
            }
            cnt += __popcll(mask);
        }
        const int ccnt = min(cnt, CAP);

        // ---- Phase B: dense KAN over compacted pairs (~23) ----
        for (int i = lane; i < ccnt; i += 64) {
            const int n = s_idx[wave][i];
            const float2 p = s_nodes[n];
            const float dx = x0 - p.x;
            const float dy = x1 - p.y;
            const float d2 = fmaf(dx, dx, dy * dy);
            const float pw = kan_phi(dx, dy, d2, s_w1a, s_w1b, s_w2);
            s1 += pw;
            s2 += pw * s_w[n];
        }

        // ---- wave reduction ----
        #pragma unroll
        for (int off = 32; off; off >>= 1) {
            s1 += __shfl_down(s1, off);
            s2 += __shfl_down(s2, off);
        }
        const float phi_sum = __shfl(s1, 0);
        const float num     = __shfl(s2, 0);

        if (phi_sum < 1e-14f) {
            // ---- orphan: exp-weighted 8-NN fallback (wave-uniform, rare) ----
            // Keys order by d^2 (monotone in d); all d2 > 0 here since no
            // node is within radius, so keys are strictly increasing.
            const float alpha = (float)(20.0 / 0.06);
            unsigned long long last = 0ull;
            float accw = 0.0f, accwv = 0.0f;
            const int kk = (N < 8) ? N : 8;
            for (int sel = 0; sel < kk; ++sel) {
                unsigned long long best = ~0ull;
                for (int k = 0; k < KITER; ++k) {
                    const int n = lane + (k << 6);
                    const float2 p = s_nodes[n];
                    const float dx = x0 - p.x;
                    const float dy = x1 - p.y;
                    const float d2 = fmaf(dx, dx, dy * dy);
                    const unsigned long long key =
                        ((unsigned long long)__float_as_uint(d2) << 32) |
                        (unsigned)n;
                    if (key > last && key < best) best = key;
                }
                // wave-min, butterfly so every lane holds the result
                #pragma unroll
                for (int off = 32; off; off >>= 1) {
                    unsigned lo = (unsigned)best, hi = (unsigned)(best >> 32);
                    unsigned olo = __shfl_xor(lo, off);
                    unsigned ohi = __shfl_xor(hi, off);
                    unsigned long long other =
                        ((unsigned long long)ohi << 32) | olo;
                    if (other < best) best = other;
                }
                last = best;
                const float dk = sqrtf(__uint_as_float((unsigned)(best >> 32)));
                const int idx = (int)(best & 0xffffffffu);
                const float wk = expf(-alpha * dk);
                accw += wk;
                accwv += wk * s_w[idx];
            }
            if (lane == 0) out[m] = accwv / (accw + 1e-18f);
        } else {
            if (lane == 0) out[m] = num / (phi_sum + 1e-12f);
        }
    }
}

extern "C" void kernel_launch(void* const* d_in, const int* in_sizes, int n_in,
                              void* d_out, int out_size, void* d_ws, size_t ws_size,
                              hipStream_t stream) {
    const float* x     = (const float*)d_in[0];
    const float* nodes = (const float*)d_in[1];
    const float* w     = (const float*)d_in[2];
    const float* w1a   = (const float*)d_in[3];
    const float* w1b   = (const float*)d_in[4];
    const float* w2    = (const float*)d_in[5];
    const int M = in_sizes[0] / 2;
    const int N = in_sizes[1] / 2;
    float* out = (float*)d_out;
    const int nblocks = (M + ROWS - 1) / ROWS;
    meshfree_kan_kernel<<<dim3(nblocks), dim3(256), 0, stream>>>(
        x, nodes, w, w1a, w1b, w2, out, M, N);
}